// Round 2
// baseline (532.412 us; speedup 1.0000x reference)
//
#include <hip/hip_runtime.h>
#include <hip/hip_bf16.h>
#include <cmath>

// ---------------------------------------------------------------------------
// BeliefTransformerBlock: LN1 -> QKV -> masked attention -> LN2 -> FC+GELU -> proj
// B=32, N=1024, D=512.  All GEMMs via mfma_f32_16x16x32_f16, fp32 accumulate.
//
// Memory plan (round 1): d_ws requirement reduced 306MB -> 100MB + adaptive
// score chunk. d_out (64 MiB) doubles as scratch:
//   d_out[ 0:32MiB) : h (LN1 out, fp16)  -> later vT (fp16)   [h dead after QKV]
//   d_out[32:64MiB) : y (attention out, fp16)
// d_ws:
//   0MB: wqkvT(1.5) 2MB: wfcT(.5) 3MB: wprojT(.5)
//   4MB: qkv (96MB fp16) -> after attention reused: ln2o @4MB, gelub @36MB
//   100MB: scores chunk (CB batches * 4MB fp32), CB adapted to ws_size
// ---------------------------------------------------------------------------

using f16 = _Float16;
typedef _Float16 f16x8 __attribute__((ext_vector_type(8)));
typedef float f32x4 __attribute__((ext_vector_type(4)));

#define NB 32
#define NN 1024
#define ND 512

// ---------------------------------------------------------------------------
// Weight cast + transpose: w[K][Ncols] fp32 -> wT[n][k] fp16
// ---------------------------------------------------------------------------
__global__ void transpose_cast_w(const float* __restrict__ w, f16* __restrict__ wT,
                                 int K, int Ncols) {
    __shared__ float tile[32][33];
    const int n0 = blockIdx.x * 32, k0 = blockIdx.y * 32;
    const int tx = threadIdx.x, ty = threadIdx.y;
    for (int i = ty; i < 32; i += 8)
        tile[i][tx] = w[(long long)(k0 + i) * Ncols + n0 + tx];
    __syncthreads();
    for (int i = ty; i < 32; i += 8)
        wT[(long long)(n0 + i) * K + k0 + tx] = (f16)tile[tx][i];
}

// ---------------------------------------------------------------------------
// V transpose per batch: v[b][k][d] (inside qkv, col offset 1024, ld 1536)
//                     -> vT[b][d][k] (ld 1024)
// ---------------------------------------------------------------------------
__global__ void transpose_v(const f16* __restrict__ qkv, f16* __restrict__ vT) {
    __shared__ f16 tile[32][33];
    const int d0 = blockIdx.x * 32, k0 = blockIdx.y * 32, b = blockIdx.z;
    const int tx = threadIdx.x, ty = threadIdx.y;
    for (int i = ty; i < 32; i += 8)
        tile[i][tx] = qkv[((long long)b * NN + k0 + i) * 1536 + 1024 + d0 + tx];
    __syncthreads();
    for (int i = ty; i < 32; i += 8)
        vT[((long long)b * ND + d0 + i) * NN + k0 + tx] = tile[tx][i];
}

// ---------------------------------------------------------------------------
// LayerNorm over last dim (512), no bias. Output fp16. One block per row.
// ---------------------------------------------------------------------------
template <typename TIN>
__global__ __launch_bounds__(256) void ln_kernel(const TIN* __restrict__ x,
                                                 const float* __restrict__ gamma,
                                                 f16* __restrict__ out) {
    const int tid = threadIdx.x;
    const long long base = (long long)blockIdx.x * ND;
    float v0 = (float)x[base + 2 * tid];
    float v1 = (float)x[base + 2 * tid + 1];

    __shared__ float red[8];
    const int wave = tid >> 6, lane = tid & 63;

    float s = v0 + v1;
#pragma unroll
    for (int o = 32; o > 0; o >>= 1) s += __shfl_down(s, o, 64);
    if (lane == 0) red[wave] = s;
    __syncthreads();
    const float mean = (red[0] + red[1] + red[2] + red[3]) * (1.f / 512.f);
    __syncthreads();

    const float d0 = v0 - mean, d1 = v1 - mean;
    float q = d0 * d0 + d1 * d1;
#pragma unroll
    for (int o = 32; o > 0; o >>= 1) q += __shfl_down(q, o, 64);
    if (lane == 0) red[wave] = q;
    __syncthreads();
    const float var = (red[0] + red[1] + red[2] + red[3]) * (1.f / 512.f);
    const float rstd = rsqrtf(var + 1e-5f);

    out[base + 2 * tid]     = (f16)(d0 * rstd * gamma[2 * tid]);
    out[base + 2 * tid + 1] = (f16)(d1 * rstd * gamma[2 * tid + 1]);
}

// ---------------------------------------------------------------------------
// Masked softmax over key dim (1024). In-place: reads fp32 row, writes fp16
// probs aliased over the same row (fp16 ld = 2048 elements). One block/row.
// ---------------------------------------------------------------------------
__global__ __launch_bounds__(256) void softmax_kernel(float* __restrict__ scores,
                                                      const int* __restrict__ sizes) {
    const int b = blockIdx.y, row = blockIdx.x, tid = threadIdx.x;
    float* srow = scores + ((long long)b * NN + row) * NN;
    f16* drow = (f16*)srow;  // alias: fp16 row occupies first half of fp32 row
    const int sz = sizes[b];

    float v[4];
    float m = -1e30f;
#pragma unroll
    for (int k = 0; k < 4; k++) {
        const int c = tid + k * 256;
        v[k] = srow[c];
        if (c < sz) m = fmaxf(m, v[k]);
    }
#pragma unroll
    for (int o = 32; o > 0; o >>= 1) m = fmaxf(m, __shfl_xor(m, o, 64));
    __shared__ float red[8];
    const int wave = tid >> 6, lane = tid & 63;
    if (lane == 0) red[wave] = m;
    __syncthreads();
    m = fmaxf(fmaxf(red[0], red[1]), fmaxf(red[2], red[3]));

    float e[4];
    float s = 0.f;
#pragma unroll
    for (int k = 0; k < 4; k++) {
        const int c = tid + k * 256;
        e[k] = (c < sz) ? __expf(v[k] - m) : 0.f;
        s += e[k];
    }
#pragma unroll
    for (int o = 32; o > 0; o >>= 1) s += __shfl_xor(s, o, 64);
    __syncthreads();   // everyone done reading red[] (max) and srow
    if (lane == 0) red[wave] = s;
    __syncthreads();
    const float inv = 1.f / (red[0] + red[1] + red[2] + red[3]);
#pragma unroll
    for (int k = 0; k < 4; k++) {
        const int c = tid + k * 256;
        drow[c] = (f16)(e[k] * inv);  // all reads complete before first write
    }
}

// ---------------------------------------------------------------------------
// GEMM: C[M][N] = A[M][K] * Bt[N][K]^T.  128x128 tile, 256 threads (4 waves),
// each wave a 64x64 block of 4x4 mfma_f32_16x16x32_f16.
// MODE 0: fp16 store.  MODE 1: fp32 store * alpha.  MODE 2: exact-GELU fp16.
// ---------------------------------------------------------------------------
__device__ __forceinline__ float gelu_exact(float x) {
    return 0.5f * x * (1.f + erff(x * 0.70710678118654752f));
}

template <int MODE>
__global__ __launch_bounds__(256) void gemm_bt(
    const f16* __restrict__ A, int lda, long long strideA,
    const f16* __restrict__ Bt, int ldb, long long strideB,
    void* __restrict__ Cv, int ldc, long long strideC,
    int K, float alpha) {
    __shared__ __align__(16) f16 As[128 * 32];
    __shared__ __align__(16) f16 Bs[128 * 32];

    const int tid = threadIdx.x;
    const int wave = tid >> 6, lane = tid & 63;
    const int wr = (wave >> 1) * 64, wc = (wave & 1) * 64;
    const int lrow = lane & 15, quad = lane >> 4;
    const long long m0 = (long long)blockIdx.y * 128;
    const long long n0 = (long long)blockIdx.x * 128;
    A += (long long)blockIdx.z * strideA;
    Bt += (long long)blockIdx.z * strideB;

    f32x4 acc[4][4];
#pragma unroll
    for (int i = 0; i < 4; i++)
#pragma unroll
        for (int j = 0; j < 4; j++) acc[i][j] = (f32x4){0.f, 0.f, 0.f, 0.f};

    // staging indices: 2 passes x 256 threads x 8 f16 (16B) = 128x32 tile
    const int e0 = tid * 8;
    const int r0 = e0 >> 5, c0 = e0 & 31;
    const int e1 = (256 + tid) * 8;
    const int r1 = e1 >> 5, c1 = e1 & 31;

    for (int k0 = 0; k0 < K; k0 += 32) {
        const int4 a0 = *(const int4*)(A + (m0 + r0) * lda + k0 + c0);
        const int4 a1 = *(const int4*)(A + (m0 + r1) * lda + k0 + c1);
        const int4 b0 = *(const int4*)(Bt + (n0 + r0) * ldb + k0 + c0);
        const int4 b1 = *(const int4*)(Bt + (n0 + r1) * ldb + k0 + c1);
        __syncthreads();  // previous iteration's LDS reads complete
        *(int4*)&As[e0] = a0;
        *(int4*)&As[e1] = a1;
        *(int4*)&Bs[e0] = b0;
        *(int4*)&Bs[e1] = b1;
        __syncthreads();

        f16x8 af[4], bf[4];
#pragma unroll
        for (int i = 0; i < 4; i++)
            af[i] = *(const f16x8*)&As[(wr + i * 16 + lrow) * 32 + quad * 8];
#pragma unroll
        for (int j = 0; j < 4; j++)
            bf[j] = *(const f16x8*)&Bs[(wc + j * 16 + lrow) * 32 + quad * 8];
#pragma unroll
        for (int i = 0; i < 4; i++)
#pragma unroll
            for (int j = 0; j < 4; j++)
                acc[i][j] = __builtin_amdgcn_mfma_f32_16x16x32_f16(af[i], bf[j], acc[i][j], 0, 0, 0);
    }

    // epilogue: C/D layout col=lane&15, row=quad*4+reg
    float* Cf = (float*)Cv + (long long)blockIdx.z * strideC;
    f16* Ch = (f16*)Cv + (long long)blockIdx.z * strideC;
#pragma unroll
    for (int i = 0; i < 4; i++) {
        const long long rbase = m0 + wr + i * 16 + quad * 4;
#pragma unroll
        for (int j = 0; j < 4; j++) {
            const long long col = n0 + wc + j * 16 + lrow;
#pragma unroll
            for (int r = 0; r < 4; r++) {
                float vv = acc[i][j][r];
                if (MODE == 1) {
                    Cf[(rbase + r) * ldc + col] = vv * alpha;
                } else {
                    if (MODE == 2) vv = gelu_exact(vv);
                    Ch[(rbase + r) * ldc + col] = (f16)vv;
                }
            }
        }
    }
}

// ---------------------------------------------------------------------------
// Launch
// ---------------------------------------------------------------------------
extern "C" void kernel_launch(void* const* d_in, const int* in_sizes, int n_in,
                              void* d_out, int out_size, void* d_ws, size_t ws_size,
                              hipStream_t stream) {
    const float* x     = (const float*)d_in[0];
    const int*   sizes = (const int*)d_in[1];
    const float* g1    = (const float*)d_in[2];
    const float* wqkv  = (const float*)d_in[3];
    const float* g2    = (const float*)d_in[4];
    const float* wfc   = (const float*)d_in[5];
    const float* wproj = (const float*)d_in[6];
    float* out = (float*)d_out;
    char* ws = (char*)d_ws;

    // ---- d_ws layout (hard floor: 100 MiB) ----
    f16* wqkvT  = (f16*)(ws + (0ull << 20));    // 1.5 MiB
    f16* wfcT   = (f16*)(ws + (2ull << 20));    // 0.5 MiB
    f16* wprojT = (f16*)(ws + (3ull << 20));    // 0.5 MiB
    f16* qkv    = (f16*)(ws + (4ull << 20));    // 96 MiB [b][n][1536]
    float* scorebuf = (float*)(ws + (100ull << 20));  // CB*4 MiB fp32 chunk
    f16* ln2o   = (f16*)(ws + (4ull << 20));    // reuse qkv (dead after attn)
    f16* gelub  = (f16*)(ws + (36ull << 20));   // reuse qkv region

    // ---- d_out doubles as scratch ----
    f16* h  = (f16*)d_out;                       // 32 MiB: LN1 out, dead after QKV
    f16* vT = (f16*)d_out;                       // 32 MiB: overwrites h
    f16* y  = (f16*)d_out + (long long)NB * NN * ND;  // second 32 MiB

    // batches per score chunk, adapted to actual ws_size (4 MiB/batch fp32)
    long long avail = (long long)ws_size - (101ll << 20);
    int CB = (int)(avail / (4ll << 20));
    if (CB < 1) CB = 1;
    if (CB > NB) CB = NB;

    const dim3 t32x8(32, 8);

    // weights -> fp16, transposed to [n][k]
    transpose_cast_w<<<dim3(1536 / 32, 512 / 32), t32x8, 0, stream>>>(wqkv, wqkvT, 512, 1536);
    transpose_cast_w<<<dim3(512 / 32, 512 / 32), t32x8, 0, stream>>>(wfc, wfcT, 512, 512);
    transpose_cast_w<<<dim3(512 / 32, 512 / 32), t32x8, 0, stream>>>(wproj, wprojT, 512, 512);

    // LN1: x -> h (fp16, in d_out)
    ln_kernel<float><<<NB * NN, 256, 0, stream>>>(x, g1, h);

    // QKV: [32768,512] @ [512,1536] -> qkv
    gemm_bt<0><<<dim3(12, 256, 1), 256, 0, stream>>>(h, 512, 0, wqkvT, 512, 0,
                                                     qkv, 1536, 0, 512, 0.f);

    // vT[b][d][k]  (overwrites h region; h is dead)
    transpose_v<<<dim3(16, 32, NB), t32x8, 0, stream>>>(qkv, vT);

    // attention, CB batches at a time through the score chunk
    for (int b0 = 0; b0 < NB; b0 += CB) {
        const int nb = (NB - b0) < CB ? (NB - b0) : CB;
        const f16* qc = qkv + (long long)b0 * NN * 1536;

        // scores = q @ k^T / sqrt(D)
        gemm_bt<1><<<dim3(8, 8, nb), 256, 0, stream>>>(
            qc, 1536, (long long)NN * 1536, qc + 512, 1536, (long long)NN * 1536,
            scorebuf, NN, (long long)NN * NN, 512, 0.044194173824159216f);

        // masked softmax, fp16 probs in place (ld 2048)
        softmax_kernel<<<dim3(NN, nb), 256, 0, stream>>>(scorebuf, sizes + b0);

        // y = attn @ v
        gemm_bt<0><<<dim3(4, 8, nb), 256, 0, stream>>>(
            (const f16*)scorebuf, 2048, (long long)NN * 2048,
            vT + (long long)b0 * ND * NN, NN, (long long)ND * NN,
            y + (long long)b0 * NN * ND, ND, (long long)NN * ND, NN, 0.f);
    }

    // LN2: y -> ln2o (qkv region, dead)
    ln_kernel<f16><<<NB * NN, 256, 0, stream>>>(y, g2, ln2o);

    // FC + exact GELU
    gemm_bt<2><<<dim3(4, 256, 1), 256, 0, stream>>>(ln2o, 512, 0, wfcT, 512, 0,
                                                    gelub, 512, 0, 512, 0.f);

    // proj -> out (fp32, overwrites all of d_out; h/vT/y are dead)
    gemm_bt<1><<<dim3(4, 256, 1), 256, 0, stream>>>(gelub, 512, 0, wprojT, 512, 0,
                                                    out, 512, 0, 512, 1.0f);
}

// Round 3
// 493.993 us; speedup vs baseline: 1.0778x; 1.0778x over previous
//
#include <hip/hip_runtime.h>
#include <hip/hip_bf16.h>
#include <cmath>

// ---------------------------------------------------------------------------
// BeliefTransformerBlock: LN1 -> QKV -> masked attention -> LN2 -> FC+GELU -> proj
// B=32, N=1024, D=512.  GEMMs: mfma_f32_16x16x32_f16, fp32 accumulate,
// global_load_lds(16B) staging (m97 structure). Mask-aware attention skipping.
//
// d_out doubles as scratch:
//   d_out[ 0:32MiB) : h (LN1 out, fp16)  -> later vT (fp16)   [h dead after QKV]
//   d_out[32:64MiB) : y (attention out, fp16)
// d_ws:
//   0MB: wqkvT(1.5) 2MB: wfcT(.5) 3MB: wprojT(.5)
//   4MB: qkv (96MB fp16) -> after attention reused: ln2o @4MB, gelub @36MB
//   100MB: scores chunk (CB batches * 4MB fp32), CB adapted to ws_size
// ---------------------------------------------------------------------------

using f16 = _Float16;
typedef _Float16 f16x8 __attribute__((ext_vector_type(8)));
typedef _Float16 f16x2 __attribute__((ext_vector_type(2)));
typedef float f32x4 __attribute__((ext_vector_type(4)));

#define NB 32
#define NN 1024
#define ND 512

// async 16B global -> LDS (lds dst must be wave-uniform base + lane*16; our
// staging layout is exactly tid*16 contiguous, so this holds)
#define GLOAD_LDS16(g, l)                                                     \
    __builtin_amdgcn_global_load_lds(                                         \
        (const __attribute__((address_space(1))) void*)(g),                   \
        (__attribute__((address_space(3))) void*)(l), 16, 0, 0)

// ---------------------------------------------------------------------------
// Weight cast + transpose: w[K][Ncols] fp32 -> wT[n][k] fp16
// ---------------------------------------------------------------------------
__global__ void transpose_cast_w(const float* __restrict__ w, f16* __restrict__ wT,
                                 int K, int Ncols) {
    __shared__ float tile[32][33];
    const int n0 = blockIdx.x * 32, k0 = blockIdx.y * 32;
    const int tx = threadIdx.x, ty = threadIdx.y;
    for (int i = ty; i < 32; i += 8)
        tile[i][tx] = w[(long long)(k0 + i) * Ncols + n0 + tx];
    __syncthreads();
    for (int i = ty; i < 32; i += 8)
        wT[(long long)(n0 + i) * K + k0 + tx] = (f16)tile[tx][i];
}

// ---------------------------------------------------------------------------
// V transpose per batch: v[b][k][d] (inside qkv, col offset 1024, ld 1536)
//                     -> vT[b][d][k] (ld 1024)
// ---------------------------------------------------------------------------
__global__ void transpose_v(const f16* __restrict__ qkv, f16* __restrict__ vT) {
    __shared__ f16 tile[32][33];
    const int d0 = blockIdx.x * 32, k0 = blockIdx.y * 32, b = blockIdx.z;
    const int tx = threadIdx.x, ty = threadIdx.y;
    for (int i = ty; i < 32; i += 8)
        tile[i][tx] = qkv[((long long)b * NN + k0 + i) * 1536 + 1024 + d0 + tx];
    __syncthreads();
    for (int i = ty; i < 32; i += 8)
        vT[((long long)b * ND + d0 + i) * NN + k0 + tx] = tile[tx][i];
}

// ---------------------------------------------------------------------------
// LayerNorm over last dim (512), no bias. Output fp16. One block per row.
// ---------------------------------------------------------------------------
template <typename TIN>
__global__ __launch_bounds__(256) void ln_kernel(const TIN* __restrict__ x,
                                                 const float* __restrict__ gamma,
                                                 f16* __restrict__ out) {
    const int tid = threadIdx.x;
    const long long base = (long long)blockIdx.x * ND;
    float v0, v1;
    if constexpr (sizeof(TIN) == 4) {
        const float2 t = ((const float2*)(x + base))[tid];
        v0 = t.x; v1 = t.y;
    } else {
        const f16x2 t = ((const f16x2*)(x + base))[tid];
        v0 = (float)t.x; v1 = (float)t.y;
    }

    __shared__ float red[8];
    const int wave = tid >> 6, lane = tid & 63;

    float s = v0 + v1;
#pragma unroll
    for (int o = 32; o > 0; o >>= 1) s += __shfl_down(s, o, 64);
    if (lane == 0) red[wave] = s;
    __syncthreads();
    const float mean = (red[0] + red[1] + red[2] + red[3]) * (1.f / 512.f);
    __syncthreads();

    const float d0 = v0 - mean, d1 = v1 - mean;
    float q = d0 * d0 + d1 * d1;
#pragma unroll
    for (int o = 32; o > 0; o >>= 1) q += __shfl_down(q, o, 64);
    if (lane == 0) red[wave] = q;
    __syncthreads();
    const float var = (red[0] + red[1] + red[2] + red[3]) * (1.f / 512.f);
    const float rstd = rsqrtf(var + 1e-5f);

    f16x2 o2;
    o2.x = (f16)(d0 * rstd * gamma[2 * tid]);
    o2.y = (f16)(d1 * rstd * gamma[2 * tid + 1]);
    ((f16x2*)(out + base))[tid] = o2;
}

// ---------------------------------------------------------------------------
// Masked softmax over key dim (1024). In-place: reads fp32 row (only c < sz),
// writes fp16 probs aliased over the same row (ld 2048), only c < round32(sz).
// ---------------------------------------------------------------------------
__global__ __launch_bounds__(256) void softmax_kernel(float* __restrict__ scores,
                                                      const int* __restrict__ sizes) {
    const int b = blockIdx.y, row = blockIdx.x, tid = threadIdx.x;
    float* srow = scores + ((long long)b * NN + row) * NN;
    f16* drow = (f16*)srow;  // alias: fp16 row occupies first half of fp32 row
    const int sz = sizes[b];
    const int keff = (sz + 31) & ~31;  // attn@V reads exactly k < keff

    float v[4];
    float m = -1e30f;
#pragma unroll
    for (int k = 0; k < 4; k++) {
        const int c = tid + k * 256;
        v[k] = (c < sz) ? srow[c] : 0.f;
        if (c < sz) m = fmaxf(m, v[k]);
    }
#pragma unroll
    for (int o = 32; o > 0; o >>= 1) m = fmaxf(m, __shfl_xor(m, o, 64));
    __shared__ float red[8];
    const int wave = tid >> 6, lane = tid & 63;
    if (lane == 0) red[wave] = m;
    __syncthreads();
    m = fmaxf(fmaxf(red[0], red[1]), fmaxf(red[2], red[3]));

    float e[4];
    float s = 0.f;
#pragma unroll
    for (int k = 0; k < 4; k++) {
        const int c = tid + k * 256;
        e[k] = (c < sz) ? __expf(v[k] - m) : 0.f;
        s += e[k];
    }
#pragma unroll
    for (int o = 32; o > 0; o >>= 1) s += __shfl_xor(s, o, 64);
    __syncthreads();   // everyone done reading red[] (max) and srow
    if (lane == 0) red[wave] = s;
    __syncthreads();
    const float inv = 1.f / (red[0] + red[1] + red[2] + red[3]);
#pragma unroll
    for (int k = 0; k < 4; k++) {
        const int c = tid + k * 256;
        if (c < keff) drow[c] = (f16)(e[k] * inv);  // reads done (syncs above)
    }
}

// ---------------------------------------------------------------------------
// GEMM: C[M][N] = A[M][K] * Bt[N][K]^T.  128x128 tile, 256 threads (4 waves),
// each wave 64x64 of 4x4 mfma_f32_16x16x32_f16. global_load_lds(16B) staging.
// MODE 0: fp16 store.  MODE 1: fp32 store * alpha.  MODE 2: exact-GELU fp16.
// MASKN: skip whole block if n0 >= sizes[z] (masked score columns).
// MASKK: bound K at round32(sizes[z]) (probs are exactly 0 beyond).
// ---------------------------------------------------------------------------
__device__ __forceinline__ float gelu_exact(float x) {
    return 0.5f * x * (1.f + erff(x * 0.70710678118654752f));
}

template <int MODE, int MASKN, int MASKK>
__global__ __launch_bounds__(256) void gemm_bt(
    const f16* __restrict__ A, int lda, long long strideA,
    const f16* __restrict__ Bt, int ldb, long long strideB,
    void* __restrict__ Cv, int ldc, long long strideC,
    int K, float alpha, const int* __restrict__ sizes) {
    __shared__ __align__(16) f16 As[128 * 32];
    __shared__ __align__(16) f16 Bs[128 * 32];

    const int tid = threadIdx.x;
    const int wave = tid >> 6, lane = tid & 63;
    const int wr = (wave >> 1) * 64, wc = (wave & 1) * 64;
    const int lrow = lane & 15, quad = lane >> 4;
    const long long m0 = (long long)blockIdx.y * 128;
    const long long n0 = (long long)blockIdx.x * 128;

    if (MASKN) {  // block-uniform: all columns masked -> nothing to compute
        if (n0 >= sizes[blockIdx.z]) return;
    }
    int Keff = K;
    if (MASKK) {
        const int ke = (sizes[blockIdx.z] + 31) & ~31;
        if (ke < Keff) Keff = ke;
    }

    A += (long long)blockIdx.z * strideA;
    Bt += (long long)blockIdx.z * strideB;

    f32x4 acc[4][4];
#pragma unroll
    for (int i = 0; i < 4; i++)
#pragma unroll
        for (int j = 0; j < 4; j++) acc[i][j] = (f32x4){0.f, 0.f, 0.f, 0.f};

    // staging indices: 2 passes x 256 threads x 8 f16 (16B) = 128x32 tile
    const int e0 = tid * 8;
    const int r0 = e0 >> 5, c0 = e0 & 31;
    const int e1 = (256 + tid) * 8;
    const int r1 = e1 >> 5, c1 = e1 & 31;

    const f16* Ar0 = A + (m0 + r0) * lda + c0;
    const f16* Ar1 = A + (m0 + r1) * lda + c1;
    const f16* Br0 = Bt + (n0 + r0) * ldb + c0;
    const f16* Br1 = Bt + (n0 + r1) * ldb + c1;

    for (int k0 = 0; k0 < Keff; k0 += 32) {
        __syncthreads();  // previous iteration's LDS reads complete
        GLOAD_LDS16(Ar0 + k0, &As[e0]);
        GLOAD_LDS16(Ar1 + k0, &As[e1]);
        GLOAD_LDS16(Br0 + k0, &Bs[e0]);
        GLOAD_LDS16(Br1 + k0, &Bs[e1]);
        __syncthreads();  // compiler drains vmcnt before barrier -> data landed

        f16x8 af[4], bf[4];
#pragma unroll
        for (int i = 0; i < 4; i++)
            af[i] = *(const f16x8*)&As[(wr + i * 16 + lrow) * 32 + quad * 8];
#pragma unroll
        for (int j = 0; j < 4; j++)
            bf[j] = *(const f16x8*)&Bs[(wc + j * 16 + lrow) * 32 + quad * 8];
#pragma unroll
        for (int i = 0; i < 4; i++)
#pragma unroll
            for (int j = 0; j < 4; j++)
                acc[i][j] = __builtin_amdgcn_mfma_f32_16x16x32_f16(af[i], bf[j], acc[i][j], 0, 0, 0);
    }

    // epilogue: C/D layout col=lane&15, row=quad*4+reg
    float* Cf = (float*)Cv + (long long)blockIdx.z * strideC;
    f16* Ch = (f16*)Cv + (long long)blockIdx.z * strideC;
#pragma unroll
    for (int i = 0; i < 4; i++) {
        const long long rbase = m0 + wr + i * 16 + quad * 4;
#pragma unroll
        for (int j = 0; j < 4; j++) {
            const long long col = n0 + wc + j * 16 + lrow;
#pragma unroll
            for (int r = 0; r < 4; r++) {
                float vv = acc[i][j][r];
                if (MODE == 1) {
                    Cf[(rbase + r) * ldc + col] = vv * alpha;
                } else {
                    if (MODE == 2) vv = gelu_exact(vv);
                    Ch[(rbase + r) * ldc + col] = (f16)vv;
                }
            }
        }
    }
}

// ---------------------------------------------------------------------------
// Launch
// ---------------------------------------------------------------------------
extern "C" void kernel_launch(void* const* d_in, const int* in_sizes, int n_in,
                              void* d_out, int out_size, void* d_ws, size_t ws_size,
                              hipStream_t stream) {
    const float* x     = (const float*)d_in[0];
    const int*   sizes = (const int*)d_in[1];
    const float* g1    = (const float*)d_in[2];
    const float* wqkv  = (const float*)d_in[3];
    const float* g2    = (const float*)d_in[4];
    const float* wfc   = (const float*)d_in[5];
    const float* wproj = (const float*)d_in[6];
    float* out = (float*)d_out;
    char* ws = (char*)d_ws;

    // ---- d_ws layout (hard floor: 100 MiB) ----
    f16* wqkvT  = (f16*)(ws + (0ull << 20));    // 1.5 MiB
    f16* wfcT   = (f16*)(ws + (2ull << 20));    // 0.5 MiB
    f16* wprojT = (f16*)(ws + (3ull << 20));    // 0.5 MiB
    f16* qkv    = (f16*)(ws + (4ull << 20));    // 96 MiB [b][n][1536]
    float* scorebuf = (float*)(ws + (100ull << 20));  // CB*4 MiB fp32 chunk
    f16* ln2o   = (f16*)(ws + (4ull << 20));    // reuse qkv (dead after attn)
    f16* gelub  = (f16*)(ws + (36ull << 20));   // reuse qkv region

    // ---- d_out doubles as scratch ----
    f16* h  = (f16*)d_out;                       // 32 MiB: LN1 out, dead after QKV
    f16* vT = (f16*)d_out;                       // 32 MiB: overwrites h
    f16* y  = (f16*)d_out + (long long)NB * NN * ND;  // second 32 MiB

    // batches per score chunk, adapted to actual ws_size (4 MiB/batch fp32)
    long long avail = (long long)ws_size - (101ll << 20);
    int CB = (int)(avail / (4ll << 20));
    if (CB < 1) CB = 1;
    if (CB > NB) CB = NB;

    const dim3 t32x8(32, 8);

    // weights -> fp16, transposed to [n][k]
    transpose_cast_w<<<dim3(1536 / 32, 512 / 32), t32x8, 0, stream>>>(wqkv, wqkvT, 512, 1536);
    transpose_cast_w<<<dim3(512 / 32, 512 / 32), t32x8, 0, stream>>>(wfc, wfcT, 512, 512);
    transpose_cast_w<<<dim3(512 / 32, 512 / 32), t32x8, 0, stream>>>(wproj, wprojT, 512, 512);

    // LN1: x -> h (fp16, in d_out)
    ln_kernel<float><<<NB * NN, 256, 0, stream>>>(x, g1, h);

    // QKV: [32768,512] @ [512,1536] -> qkv
    gemm_bt<0, 0, 0><<<dim3(12, 256, 1), 256, 0, stream>>>(
        h, 512, 0, wqkvT, 512, 0, qkv, 1536, 0, 512, 0.f, nullptr);

    // vT[b][d][k]  (overwrites h region; h is dead)
    transpose_v<<<dim3(16, 32, NB), t32x8, 0, stream>>>(qkv, vT);

    // attention, CB batches at a time through the score chunk
    for (int b0 = 0; b0 < NB; b0 += CB) {
        const int nb = (NB - b0) < CB ? (NB - b0) : CB;
        const f16* qc = qkv + (long long)b0 * NN * 1536;

        // scores = q @ k^T / sqrt(D); skip column-blocks >= size
        gemm_bt<1, 1, 0><<<dim3(8, 8, nb), 256, 0, stream>>>(
            qc, 1536, (long long)NN * 1536, qc + 512, 1536, (long long)NN * 1536,
            scorebuf, NN, (long long)NN * NN, 512, 0.044194173824159216f, sizes + b0);

        // masked softmax, fp16 probs in place (ld 2048)
        softmax_kernel<<<dim3(NN, nb), 256, 0, stream>>>(scorebuf, sizes + b0);

        // y = attn @ v; K bounded at round32(size)
        gemm_bt<0, 0, 1><<<dim3(4, 8, nb), 256, 0, stream>>>(
            (const f16*)scorebuf, 2048, (long long)NN * 2048,
            vT + (long long)b0 * ND * NN, NN, (long long)ND * NN,
            y + (long long)b0 * NN * ND, ND, (long long)NN * ND, NN, 0.f, sizes + b0);
    }

    // LN2: y -> ln2o (qkv region, dead)
    ln_kernel<f16><<<NB * NN, 256, 0, stream>>>(y, g2, ln2o);

    // FC + exact GELU
    gemm_bt<2, 0, 0><<<dim3(4, 256, 1), 256, 0, stream>>>(
        ln2o, 512, 0, wfcT, 512, 0, gelub, 512, 0, 512, 0.f, nullptr);

    // proj -> out (fp32, overwrites all of d_out; h/vT/y are dead)
    gemm_bt<1, 0, 0><<<dim3(4, 256, 1), 256, 0, stream>>>(
        gelub, 512, 0, wprojT, 512, 0, out, 512, 0, 512, 1.0f, nullptr);
}

// Round 5
// 453.292 us; speedup vs baseline: 1.1745x; 1.0898x over previous
//
#include <hip/hip_runtime.h>
#include <hip/hip_bf16.h>
#include <cmath>

// ---------------------------------------------------------------------------
// BeliefTransformerBlock: LN1 -> QKV -> masked attention -> LN2 -> FC+GELU -> proj
// B=32, N=1024, D=512.  GEMMs: mfma_f32_16x16x32_f16, fp32 accumulate,
// global_load_lds(16B) staging, XOR-swizzled LDS (kills 8-way bank conflict:
// round-3 counters showed SQ_LDS_BANK_CONFLICT=6.29e6 = 2.94x LDS slowdown).
//
// d_out scratch: [0:32MiB) h (LN1 out), [32:64MiB) y (attn out)
// d_ws: 0 wqkvT(1.5) 2 wfcT(.5) 3 wprojT(.5) | 4MB qk (64MB, [b][n][1024] q|k)
//       68MB vT (32MB, [b][d][n], written by QKV epilogue) | 100MB score chunk
//       (fp16, CB*2MB).  After attention: ln2o @4MB, gelub @36MB.
// ---------------------------------------------------------------------------

using f16 = _Float16;
typedef _Float16 f16x8 __attribute__((ext_vector_type(8)));
typedef _Float16 f16x4 __attribute__((ext_vector_type(4)));
typedef _Float16 f16x2 __attribute__((ext_vector_type(2)));
typedef float f32x4 __attribute__((ext_vector_type(4)));

#define NB 32
#define NN 1024
#define ND 512

#define GLOAD_LDS16(g, l)                                                     \
    __builtin_amdgcn_global_load_lds(                                         \
        (const __attribute__((address_space(1))) void*)(g),                   \
        (__attribute__((address_space(3))) void*)(l), 16, 0, 0)

// ---------------------------------------------------------------------------
// Weight cast + transpose: w[K][Ncols] fp32 -> wT[n][k] fp16
// ---------------------------------------------------------------------------
__global__ void transpose_cast_w(const float* __restrict__ w, f16* __restrict__ wT,
                                 int K, int Ncols) {
    __shared__ float tile[32][33];
    const int n0 = blockIdx.x * 32, k0 = blockIdx.y * 32;
    const int tx = threadIdx.x, ty = threadIdx.y;
    for (int i = ty; i < 32; i += 8)
        tile[i][tx] = w[(long long)(k0 + i) * Ncols + n0 + tx];
    __syncthreads();
    for (int i = ty; i < 32; i += 8)
        wT[(long long)(n0 + i) * K + k0 + tx] = (f16)tile[tx][i];
}

// ---------------------------------------------------------------------------
// LayerNorm over last dim (512), no bias. Output fp16. One block per row.
// ---------------------------------------------------------------------------
template <typename TIN>
__global__ __launch_bounds__(256) void ln_kernel(const TIN* __restrict__ x,
                                                 const float* __restrict__ gamma,
                                                 f16* __restrict__ out) {
    const int tid = threadIdx.x;
    const long long base = (long long)blockIdx.x * ND;
    float v0, v1;
    if constexpr (sizeof(TIN) == 4) {
        const float2 t = ((const float2*)(x + base))[tid];
        v0 = t.x; v1 = t.y;
    } else {
        const f16x2 t = ((const f16x2*)(x + base))[tid];
        v0 = (float)t.x; v1 = (float)t.y;
    }

    __shared__ float red[8];
    const int wave = tid >> 6, lane = tid & 63;

    float s = v0 + v1;
#pragma unroll
    for (int o = 32; o > 0; o >>= 1) s += __shfl_down(s, o, 64);
    if (lane == 0) red[wave] = s;
    __syncthreads();
    const float mean = (red[0] + red[1] + red[2] + red[3]) * (1.f / 512.f);
    __syncthreads();

    const float d0 = v0 - mean, d1 = v1 - mean;
    float q = d0 * d0 + d1 * d1;
#pragma unroll
    for (int o = 32; o > 0; o >>= 1) q += __shfl_down(q, o, 64);
    if (lane == 0) red[wave] = q;
    __syncthreads();
    const float var = (red[0] + red[1] + red[2] + red[3]) * (1.f / 512.f);
    const float rstd = rsqrtf(var + 1e-5f);

    f16x2 o2;
    o2.x = (f16)(d0 * rstd * gamma[2 * tid]);
    o2.y = (f16)(d1 * rstd * gamma[2 * tid + 1]);
    ((f16x2*)(out + base))[tid] = o2;
}

// ---------------------------------------------------------------------------
// Masked softmax, fp16 in-place, one WAVE per row (no LDS, no barriers).
// Lane holds 16 elements. Writes only c < round32(sz) (attn@V's K bound).
// ---------------------------------------------------------------------------
__global__ __launch_bounds__(256) void softmax_wave(f16* __restrict__ scores,
                                                    const int* __restrict__ sizes) {
    const int b = blockIdx.y;
    const int wave = threadIdx.x >> 6, lane = threadIdx.x & 63;
    const int row = blockIdx.x * 4 + wave;
    f16* srow = scores + ((long long)b * NN + row) * NN;
    const int sz = sizes[b];
    const int keff = (sz + 31) & ~31;
    const int cbase = lane * 16;

    const f16x8 a0 = *(const f16x8*)&srow[cbase];
    const f16x8 a1 = *(const f16x8*)&srow[cbase + 8];
    float v[16];
#pragma unroll
    for (int e = 0; e < 8; e++) { v[e] = (float)a0[e]; v[8 + e] = (float)a1[e]; }

    float m = -1e30f;
#pragma unroll
    for (int e = 0; e < 16; e++)
        if (cbase + e < sz) m = fmaxf(m, v[e]);
#pragma unroll
    for (int o = 32; o > 0; o >>= 1) m = fmaxf(m, __shfl_xor(m, o, 64));

    float s = 0.f;
#pragma unroll
    for (int e = 0; e < 16; e++) {
        v[e] = (cbase + e < sz) ? __expf(v[e] - m) : 0.f;
        s += v[e];
    }
#pragma unroll
    for (int o = 32; o > 0; o >>= 1) s += __shfl_xor(s, o, 64);
    const float inv = 1.f / s;

    if (cbase < keff) {
        f16x8 o0, o1;
#pragma unroll
        for (int e = 0; e < 8; e++) {
            o0[e] = (f16)(v[e] * inv);
            o1[e] = (f16)(v[8 + e] * inv);
        }
        *(f16x8*)&srow[cbase] = o0;
        *(f16x8*)&srow[cbase + 8] = o1;
    }
}

// ---------------------------------------------------------------------------
// GEMM: C[M][N] = A[M][K] * Bt[N][K]^T.  128x128 tile, 4 waves, 4x4 MFMA
// 16x16x32_f16 per wave.  LDS XOR-swizzle: granule col g' = g ^ ((row>>1)&3).
// Write side keeps wave-uniform tid*16 LDS dst (global src permuted instead);
// read side banks = 16*(lrow&1)+4*(quad^((lrow>>1)&3)) -> 2x fewer collisions.
// MODE 0: fp16*alpha. 1: fp32*alpha. 2: GELU fp16. 3: QKV split (qk + vT^T).
// MASKN: skip block if n0 >= sizes[z].  MASKK: K bounded at round32(sizes[z]).
// ---------------------------------------------------------------------------
__device__ __forceinline__ float gelu_exact(float x) {
    return 0.5f * x * (1.f + erff(x * 0.70710678118654752f));
}

template <int MODE, int MASKN, int MASKK>
__global__ __launch_bounds__(256) void gemm_bt(
    const f16* __restrict__ A, int lda, long long strideA,
    const f16* __restrict__ Bt, int ldb, long long strideB,
    void* __restrict__ Cv, int ldc, long long strideC,
    int K, float alpha, const int* __restrict__ sizes, void* __restrict__ Cv2) {
    __shared__ __align__(16) f16 As[128 * 32];
    __shared__ __align__(16) f16 Bs[128 * 32];

    const int tid = threadIdx.x;
    const int wave = tid >> 6, lane = tid & 63;
    const int wr = (wave >> 1) * 64, wc = (wave & 1) * 64;
    const int lrow = lane & 15, quad = lane >> 4;
    const long long m0 = (long long)blockIdx.y * 128;
    const long long n0 = (long long)blockIdx.x * 128;

    if (MASKN) {
        if (n0 >= sizes[blockIdx.z]) return;
    }
    int Keff = K;
    if (MASKK) {
        const int ke = (sizes[blockIdx.z] + 31) & ~31;
        if (ke < Keff) Keff = ke;
    }

    A += (long long)blockIdx.z * strideA;
    Bt += (long long)blockIdx.z * strideB;

    f32x4 acc[4][4];
#pragma unroll
    for (int i = 0; i < 4; i++)
#pragma unroll
        for (int j = 0; j < 4; j++) acc[i][j] = (f32x4){0.f, 0.f, 0.f, 0.f};

    // staging: slot s holds granule (row=s>>2, gslot=s&3); source granule is
    // gcol = gslot ^ ((row>>1)&3)  (inverse of the read-side swizzle)
    const int s0 = tid, s1 = tid + 256;
    const int r0 = s0 >> 2, c0 = ((s0 & 3) ^ ((r0 >> 1) & 3)) * 8;
    const int r1 = s1 >> 2, c1 = ((s1 & 3) ^ ((r1 >> 1) & 3)) * 8;

    const f16* Ar0 = A + (m0 + r0) * lda + c0;
    const f16* Ar1 = A + (m0 + r1) * lda + c1;
    const f16* Br0 = Bt + (n0 + r0) * ldb + c0;
    const f16* Br1 = Bt + (n0 + r1) * ldb + c1;

    const int swz8 = (quad ^ ((lrow >> 1) & 3)) * 8;

    for (int k0 = 0; k0 < Keff; k0 += 32) {
        __syncthreads();
        GLOAD_LDS16(Ar0 + k0, &As[s0 * 8]);
        GLOAD_LDS16(Ar1 + k0, &As[s1 * 8]);
        GLOAD_LDS16(Br0 + k0, &Bs[s0 * 8]);
        GLOAD_LDS16(Br1 + k0, &Bs[s1 * 8]);
        __syncthreads();

        f16x8 af[4], bf[4];
#pragma unroll
        for (int i = 0; i < 4; i++)
            af[i] = *(const f16x8*)&As[(wr + i * 16 + lrow) * 32 + swz8];
#pragma unroll
        for (int j = 0; j < 4; j++)
            bf[j] = *(const f16x8*)&Bs[(wc + j * 16 + lrow) * 32 + swz8];
#pragma unroll
        for (int i = 0; i < 4; i++)
#pragma unroll
            for (int j = 0; j < 4; j++)
                acc[i][j] = __builtin_amdgcn_mfma_f32_16x16x32_f16(af[i], bf[j], acc[i][j], 0, 0, 0);
    }

    // epilogue: C/D layout col=lane&15, row=quad*4+reg
    if (MODE == 3 && n0 >= 1024) {
        // V columns: store transposed into vT[b][d][n] as packed rows
        f16* vTp = (f16*)Cv2;
#pragma unroll
        for (int i = 0; i < 4; i++) {
            const long long rbase = m0 + wr + i * 16 + quad * 4;
            const long long bb = rbase >> 10;
            const long long nrow = rbase & 1023;
#pragma unroll
            for (int j = 0; j < 4; j++) {
                const long long col = n0 + wc + j * 16 + lrow - 1024;
                f16x4 pk;
#pragma unroll
                for (int r = 0; r < 4; r++) pk[r] = (f16)acc[i][j][r];
                *(f16x4*)&vTp[bb * ND * NN + col * NN + nrow] = pk;
            }
        }
        return;
    }
    float* Cf = (float*)Cv + (long long)blockIdx.z * strideC;
    f16* Ch = (f16*)Cv + (long long)blockIdx.z * strideC;
#pragma unroll
    for (int i = 0; i < 4; i++) {
        const long long rbase = m0 + wr + i * 16 + quad * 4;
#pragma unroll
        for (int j = 0; j < 4; j++) {
            const long long col = n0 + wc + j * 16 + lrow;
#pragma unroll
            for (int r = 0; r < 4; r++) {
                float vv = acc[i][j][r];
                if (MODE == 1) {
                    Cf[(rbase + r) * ldc + col] = vv * alpha;
                } else if (MODE == 2) {
                    Ch[(rbase + r) * ldc + col] = (f16)gelu_exact(vv);
                } else {
                    Ch[(rbase + r) * ldc + col] = (f16)(vv * alpha);
                }
            }
        }
    }
}

// ---------------------------------------------------------------------------
// Launch
// ---------------------------------------------------------------------------
extern "C" void kernel_launch(void* const* d_in, const int* in_sizes, int n_in,
                              void* d_out, int out_size, void* d_ws, size_t ws_size,
                              hipStream_t stream) {
    const float* x     = (const float*)d_in[0];
    const int*   sizes = (const int*)d_in[1];
    const float* g1    = (const float*)d_in[2];
    const float* wqkv  = (const float*)d_in[3];
    const float* g2    = (const float*)d_in[4];
    const float* wfc   = (const float*)d_in[5];
    const float* wproj = (const float*)d_in[6];
    float* out = (float*)d_out;
    char* ws = (char*)d_ws;

    // ---- d_ws layout (floor: ~102 MiB) ----
    f16* wqkvT  = (f16*)(ws + (0ull << 20));    // 1.5 MiB  [1536][512]
    f16* wfcT   = (f16*)(ws + (2ull << 20));    // 0.5 MiB
    f16* wprojT = (f16*)(ws + (3ull << 20));    // 0.5 MiB
    f16* qk     = (f16*)(ws + (4ull << 20));    // 64 MiB [b][n][1024] (q|k)
    f16* vT     = (f16*)(ws + (68ull << 20));   // 32 MiB [b][d][n]
    f16* scoreb = (f16*)(ws + (100ull << 20));  // CB * 2 MiB fp16
    f16* ln2o   = (f16*)(ws + (4ull << 20));    // reuse qk (dead after attn)
    f16* gelub  = (f16*)(ws + (36ull << 20));   // reuse qk region

    // ---- d_out scratch ----
    f16* h = (f16*)d_out;                            // LN1 out, dead after QKV
    f16* y = (f16*)d_out + (long long)NB * NN * ND;  // attn out

    long long avail = (long long)ws_size - (100ll << 20);
    int CB = (int)(avail / (2ll << 20));
    if (CB < 1) CB = 1;
    if (CB > NB) CB = NB;

    const dim3 t32x8(32, 8);

    transpose_cast_w<<<dim3(48, 16), t32x8, 0, stream>>>(wqkv, wqkvT, 512, 1536);
    transpose_cast_w<<<dim3(16, 16), t32x8, 0, stream>>>(wfc, wfcT, 512, 512);
    transpose_cast_w<<<dim3(16, 16), t32x8, 0, stream>>>(wproj, wprojT, 512, 512);

    // LN1: x -> h
    ln_kernel<float><<<NB * NN, 256, 0, stream>>>(x, g1, h);

    // QKV: q,k -> qk[b][n][1024]; v -> vT[b][d][n] (fused transpose)
    gemm_bt<3, 0, 0><<<dim3(12, 256, 1), 256, 0, stream>>>(
        h, 512, 0, wqkvT, 512, 0, qk, 1024, 0, 512, 1.0f, nullptr, vT);

    // attention, CB batches per score chunk
    for (int b0 = 0; b0 < NB; b0 += CB) {
        const int nb = (NB - b0) < CB ? (NB - b0) : CB;
        const f16* qc = qk + (long long)b0 * NN * 1024;

        // scores (fp16) = q @ k^T / sqrt(D); skip fully-masked column blocks
        gemm_bt<0, 1, 0><<<dim3(8, 8, nb), 256, 0, stream>>>(
            qc, 1024, (long long)NN * 1024, qc + 512, 1024, (long long)NN * 1024,
            scoreb, 1024, (long long)NN * 1024, 512, 0.044194173824159216f,
            sizes + b0, nullptr);

        // masked softmax in place (wave per row)
        softmax_wave<<<dim3(NN / 4, nb), 256, 0, stream>>>(scoreb, sizes + b0);

        // y = attn @ v; K bounded at round32(size)
        gemm_bt<0, 0, 1><<<dim3(4, 8, nb), 256, 0, stream>>>(
            scoreb, 1024, (long long)NN * 1024,
            vT + (long long)b0 * ND * NN, NN, (long long)ND * NN,
            y + (long long)b0 * NN * ND, ND, (long long)NN * ND, NN, 1.0f,
            sizes + b0, nullptr);
    }

    // LN2: y -> ln2o
    ln_kernel<f16><<<NB * NN, 256, 0, stream>>>(y, g2, ln2o);

    // FC + exact GELU
    gemm_bt<2, 0, 0><<<dim3(4, 256, 1), 256, 0, stream>>>(
        ln2o, 512, 0, wfcT, 512, 0, gelub, 512, 0, 512, 1.0f, nullptr, nullptr);

    // proj -> out (fp32)
    gemm_bt<1, 0, 0><<<dim3(4, 256, 1), 256, 0, stream>>>(
        gelub, 512, 0, wprojT, 512, 0, out, 512, 0, 512, 1.0f, nullptr, nullptr);
}

// Round 6
// 448.184 us; speedup vs baseline: 1.1879x; 1.0114x over previous
//
#include <hip/hip_runtime.h>
#include <hip/hip_bf16.h>
#include <cmath>

// ---------------------------------------------------------------------------
// BeliefTransformerBlock: LN1 -> QKV -> masked attention -> LN2 -> FC+GELU -> proj
// B=32, N=1024, D=512.  GEMMs: mfma_f32_16x16x32_f16, fp32 accumulate,
// global_load_lds(16B) staging, BK=64 K-loop (half the barrier drains of BK=32),
// XOR-swizzled LDS (g' = g ^ (row&7); 2-way conflicts only = free per m136).
//
// Fixed two-phase attention -> NO dependence on ws_size beyond the proven
// 100 MiB floor, and no tiny-grid chunk loops:
//   phase A: scores(b=0..15)  -> d_out[0:32MiB)   (h region, dead after QKV)
//   phase B: scores(b=16..31) -> ws+4MiB          (qk[0..15], dead after A)
// d_out: [0:32) h -> scoresA ; [32:64) y (attn out)
// d_ws:  0 weights(4) | 4 qk (64, [b][n][1024] q|k) | 68 vT (32, [b][d][n])
//        after attention: ln2o @36 (qk hi, dead), gelub @4 (scoresB, dead)
// ---------------------------------------------------------------------------

using f16 = _Float16;
typedef _Float16 f16x8 __attribute__((ext_vector_type(8)));
typedef _Float16 f16x4 __attribute__((ext_vector_type(4)));
typedef _Float16 f16x2 __attribute__((ext_vector_type(2)));
typedef float f32x4 __attribute__((ext_vector_type(4)));

#define NB 32
#define NN 1024
#define ND 512

#define GLOAD_LDS16(g, l)                                                     \
    __builtin_amdgcn_global_load_lds(                                         \
        (const __attribute__((address_space(1))) void*)(g),                   \
        (__attribute__((address_space(3))) void*)(l), 16, 0, 0)

// ---------------------------------------------------------------------------
// All three weights cast + transposed in ONE launch. z: 0=qkv 1=fc 2=proj.
// ---------------------------------------------------------------------------
__global__ void transpose_cast_all(const float* __restrict__ wqkv, f16* __restrict__ wqkvT,
                                   const float* __restrict__ wfc, f16* __restrict__ wfcT,
                                   const float* __restrict__ wproj, f16* __restrict__ wprojT) {
    const int z = blockIdx.z;
    const float* w = (z == 0) ? wqkv : (z == 1) ? wfc : wproj;
    f16* wT       = (z == 0) ? wqkvT : (z == 1) ? wfcT : wprojT;
    const int Ncols = (z == 0) ? 1536 : 512;
    if ((int)blockIdx.x * 32 >= Ncols) return;

    __shared__ float tile[32][33];
    const int n0 = blockIdx.x * 32, k0 = blockIdx.y * 32;
    const int tx = threadIdx.x, ty = threadIdx.y;
    for (int i = ty; i < 32; i += 8)
        tile[i][tx] = w[(long long)(k0 + i) * Ncols + n0 + tx];
    __syncthreads();
    for (int i = ty; i < 32; i += 8)
        wT[(long long)(n0 + i) * 512 + k0 + tx] = (f16)tile[tx][i];
}

// ---------------------------------------------------------------------------
// LayerNorm over last dim (512), no bias. Output fp16. One block per row.
// ---------------------------------------------------------------------------
template <typename TIN>
__global__ __launch_bounds__(256) void ln_kernel(const TIN* __restrict__ x,
                                                 const float* __restrict__ gamma,
                                                 f16* __restrict__ out) {
    const int tid = threadIdx.x;
    const long long base = (long long)blockIdx.x * ND;
    float v0, v1;
    if constexpr (sizeof(TIN) == 4) {
        const float2 t = ((const float2*)(x + base))[tid];
        v0 = t.x; v1 = t.y;
    } else {
        const f16x2 t = ((const f16x2*)(x + base))[tid];
        v0 = (float)t.x; v1 = (float)t.y;
    }

    __shared__ float red[8];
    const int wave = tid >> 6, lane = tid & 63;

    float s = v0 + v1;
#pragma unroll
    for (int o = 32; o > 0; o >>= 1) s += __shfl_down(s, o, 64);
    if (lane == 0) red[wave] = s;
    __syncthreads();
    const float mean = (red[0] + red[1] + red[2] + red[3]) * (1.f / 512.f);
    __syncthreads();

    const float d0 = v0 - mean, d1 = v1 - mean;
    float q = d0 * d0 + d1 * d1;
#pragma unroll
    for (int o = 32; o > 0; o >>= 1) q += __shfl_down(q, o, 64);
    if (lane == 0) red[wave] = q;
    __syncthreads();
    const float var = (red[0] + red[1] + red[2] + red[3]) * (1.f / 512.f);
    const float rstd = rsqrtf(var + 1e-5f);

    f16x2 o2;
    o2.x = (f16)(d0 * rstd * gamma[2 * tid]);
    o2.y = (f16)(d1 * rstd * gamma[2 * tid + 1]);
    ((f16x2*)(out + base))[tid] = o2;
}

// ---------------------------------------------------------------------------
// Masked softmax, fp16 in-place, one WAVE per row (no LDS, no barriers).
// Writes only c < round64(sz) (attn@V's BK=64 K bound; zero-filled tail).
// ---------------------------------------------------------------------------
__global__ __launch_bounds__(256) void softmax_wave(f16* __restrict__ scores,
                                                    const int* __restrict__ sizes) {
    const int b = blockIdx.y;
    const int wave = threadIdx.x >> 6, lane = threadIdx.x & 63;
    const int row = blockIdx.x * 4 + wave;
    f16* srow = scores + ((long long)b * NN + row) * NN;
    const int sz = sizes[b];
    const int keff = (sz + 63) & ~63;
    const int cbase = lane * 16;

    const f16x8 a0 = *(const f16x8*)&srow[cbase];
    const f16x8 a1 = *(const f16x8*)&srow[cbase + 8];
    float v[16];
#pragma unroll
    for (int e = 0; e < 8; e++) { v[e] = (float)a0[e]; v[8 + e] = (float)a1[e]; }

    float m = -1e30f;
#pragma unroll
    for (int e = 0; e < 16; e++)
        if (cbase + e < sz) m = fmaxf(m, v[e]);
#pragma unroll
    for (int o = 32; o > 0; o >>= 1) m = fmaxf(m, __shfl_xor(m, o, 64));

    float s = 0.f;
#pragma unroll
    for (int e = 0; e < 16; e++) {
        v[e] = (cbase + e < sz) ? __expf(v[e] - m) : 0.f;
        s += v[e];
    }
#pragma unroll
    for (int o = 32; o > 0; o >>= 1) s += __shfl_xor(s, o, 64);
    const float inv = 1.f / s;

    if (cbase < keff) {
        f16x8 o0, o1;
#pragma unroll
        for (int e = 0; e < 8; e++) {
            o0[e] = (f16)(v[e] * inv);
            o1[e] = (f16)(v[8 + e] * inv);
        }
        *(f16x8*)&srow[cbase] = o0;
        *(f16x8*)&srow[cbase + 8] = o1;
    }
}

// ---------------------------------------------------------------------------
// GEMM: C[M][N] = A[M][K] * Bt[N][K]^T.  128x128 tile, 4 waves, 4x4 MFMA
// 16x16x32_f16 per wave, BK=64 (8 barrier pairs for K=512 instead of 16).
// LDS granule swizzle g' = g ^ (row&7); glds dst stays wave-uniform tid*16.
// MODE 0: fp16*alpha. 1: fp32*alpha. 2: GELU fp16. 3: QKV split (qk + vT^T).
// MASKN: skip block if n0 >= sizes[z].  MASKK: K bounded at round64(sizes[z]).
// ---------------------------------------------------------------------------
__device__ __forceinline__ float gelu_exact(float x) {
    return 0.5f * x * (1.f + erff(x * 0.70710678118654752f));
}

template <int MODE, int MASKN, int MASKK>
__global__ __launch_bounds__(256) void gemm_bt(
    const f16* __restrict__ A, int lda, long long strideA,
    const f16* __restrict__ Bt, int ldb, long long strideB,
    void* __restrict__ Cv, int ldc, long long strideC,
    int K, float alpha, const int* __restrict__ sizes, void* __restrict__ Cv2) {
    __shared__ __align__(16) f16 As[128 * 64];
    __shared__ __align__(16) f16 Bs[128 * 64];

    const int tid = threadIdx.x;
    const int wave = tid >> 6, lane = tid & 63;
    const int wr = (wave >> 1) * 64, wc = (wave & 1) * 64;
    const int lrow = lane & 15, quad = lane >> 4;
    const long long m0 = (long long)blockIdx.y * 128;
    const long long n0 = (long long)blockIdx.x * 128;

    if (MASKN) {
        if (n0 >= sizes[blockIdx.z]) return;
    }
    int Keff = K;
    if (MASKK) {
        const int ke = (sizes[blockIdx.z] + 63) & ~63;
        if (ke < Keff) Keff = ke;
    }

    A += (long long)blockIdx.z * strideA;
    Bt += (long long)blockIdx.z * strideB;

    f32x4 acc[4][4];
#pragma unroll
    for (int i = 0; i < 4; i++)
#pragma unroll
        for (int j = 0; j < 4; j++) acc[i][j] = (f32x4){0.f, 0.f, 0.f, 0.f};

    // staging: 4 passes/matrix; slot s -> row=s>>3, granule g=s&7,
    // source granule gc = g ^ (row&7) (self-inverse swizzle)
    const f16* Ap[4];
    const f16* Bp[4];
#pragma unroll
    for (int p = 0; p < 4; p++) {
        const int s = tid + p * 256;
        const int r = s >> 3, c = ((s & 7) ^ (r & 7)) * 8;
        Ap[p] = A + (m0 + r) * lda + c;
        Bp[p] = Bt + (n0 + r) * ldb + c;
    }

    for (int k0 = 0; k0 < Keff; k0 += 64) {
        __syncthreads();
#pragma unroll
        for (int p = 0; p < 4; p++) GLOAD_LDS16(Ap[p] + k0, &As[(tid + p * 256) * 8]);
#pragma unroll
        for (int p = 0; p < 4; p++) GLOAD_LDS16(Bp[p] + k0, &Bs[(tid + p * 256) * 8]);
        __syncthreads();

#pragma unroll
        for (int h = 0; h < 2; h++) {
            const int gq = ((h * 4 + quad) ^ (lrow & 7)) * 8;
            f16x8 af[4], bf[4];
#pragma unroll
            for (int i = 0; i < 4; i++)
                af[i] = *(const f16x8*)&As[(wr + i * 16 + lrow) * 64 + gq];
#pragma unroll
            for (int j = 0; j < 4; j++)
                bf[j] = *(const f16x8*)&Bs[(wc + j * 16 + lrow) * 64 + gq];
#pragma unroll
            for (int i = 0; i < 4; i++)
#pragma unroll
                for (int j = 0; j < 4; j++)
                    acc[i][j] = __builtin_amdgcn_mfma_f32_16x16x32_f16(af[i], bf[j], acc[i][j], 0, 0, 0);
        }
    }

    // epilogue: C/D layout col=lane&15, row=quad*4+reg
    if (MODE == 3 && n0 >= 1024) {
        // V columns: store transposed into vT[b][d][n] as packed f16x4
        f16* vTp = (f16*)Cv2;
#pragma unroll
        for (int i = 0; i < 4; i++) {
            const long long rbase = m0 + wr + i * 16 + quad * 4;
            const long long bb = rbase >> 10;
            const long long nrow = rbase & 1023;
#pragma unroll
            for (int j = 0; j < 4; j++) {
                const long long col = n0 + wc + j * 16 + lrow - 1024;
                f16x4 pk;
#pragma unroll
                for (int r = 0; r < 4; r++) pk[r] = (f16)acc[i][j][r];
                *(f16x4*)&vTp[bb * ND * NN + col * NN + nrow] = pk;
            }
        }
        return;
    }
    float* Cf = (float*)Cv + (long long)blockIdx.z * strideC;
    f16* Ch = (f16*)Cv + (long long)blockIdx.z * strideC;
#pragma unroll
    for (int i = 0; i < 4; i++) {
        const long long rbase = m0 + wr + i * 16 + quad * 4;
#pragma unroll
        for (int j = 0; j < 4; j++) {
            const long long col = n0 + wc + j * 16 + lrow;
#pragma unroll
            for (int r = 0; r < 4; r++) {
                float vv = acc[i][j][r];
                if (MODE == 1) {
                    Cf[(rbase + r) * ldc + col] = vv * alpha;
                } else if (MODE == 2) {
                    Ch[(rbase + r) * ldc + col] = (f16)gelu_exact(vv);
                } else {
                    Ch[(rbase + r) * ldc + col] = (f16)(vv * alpha);
                }
            }
        }
    }
}

// ---------------------------------------------------------------------------
// Launch
// ---------------------------------------------------------------------------
extern "C" void kernel_launch(void* const* d_in, const int* in_sizes, int n_in,
                              void* d_out, int out_size, void* d_ws, size_t ws_size,
                              hipStream_t stream) {
    const float* x     = (const float*)d_in[0];
    const int*   sizes = (const int*)d_in[1];
    const float* g1    = (const float*)d_in[2];
    const float* wqkv  = (const float*)d_in[3];
    const float* g2    = (const float*)d_in[4];
    const float* wfc   = (const float*)d_in[5];
    const float* wproj = (const float*)d_in[6];
    float* out = (float*)d_out;
    char* ws = (char*)d_ws;

    // ---- d_ws layout (floor: 100 MiB, proven available) ----
    f16* wqkvT  = (f16*)(ws + (0ull << 20));    // 1.5 MiB  [1536][512]
    f16* wfcT   = (f16*)(ws + (2ull << 20));    // 0.5 MiB
    f16* wprojT = (f16*)(ws + (3ull << 20));    // 0.5 MiB
    f16* qk     = (f16*)(ws + (4ull << 20));    // 64 MiB [b][n][1024] (q|k)
    f16* vT     = (f16*)(ws + (68ull << 20));   // 32 MiB [b][d][n]
    f16* scoresB = (f16*)(ws + (4ull << 20));   // 32 MiB (qk lo, dead after phase A)
    f16* ln2o   = (f16*)(ws + (36ull << 20));   // 32 MiB (qk hi, dead after scoresB)
    f16* gelub  = (f16*)(ws + (4ull << 20));    // 32 MiB (scoresB, dead after attnV B)

    // ---- d_out scratch ----
    f16* h       = (f16*)d_out;                            // dead after QKV
    f16* scoresA = (f16*)d_out;                            // 32 MiB (h region)
    f16* y       = (f16*)d_out + (long long)NB * NN * ND;  // attn out, 32 MiB

    const long long sstr = (long long)NN * NN;     // score batch stride
    const long long qstr = (long long)NN * 1024;   // qk batch stride
    const long long vstr = (long long)ND * NN;     // vT batch stride
    const long long ystr = (long long)NN * ND;     // y batch stride

    // weights -> fp16 transposed (one launch)
    transpose_cast_all<<<dim3(48, 16, 3), dim3(32, 8), 0, stream>>>(
        wqkv, wqkvT, wfc, wfcT, wproj, wprojT);

    // LN1: x -> h
    ln_kernel<float><<<NB * NN, 256, 0, stream>>>(x, g1, h);

    // QKV: q,k -> qk[b][n][1024]; v -> vT[b][d][n] (fused transpose)
    gemm_bt<3, 0, 0><<<dim3(12, 256, 1), 256, 0, stream>>>(
        h, 512, 0, wqkvT, 512, 0, qk, 1024, 0, 512, 1.0f, nullptr, vT);

    // ---- attention, two fixed phases of 16 batches ----
    for (int ph = 0; ph < 2; ph++) {
        const int b0 = ph * 16;
        f16* sc = ph ? scoresB : scoresA;
        const f16* qc = qk + (long long)b0 * qstr;

        // scores (fp16) = q @ k^T / sqrt(D); skip fully-masked column blocks
        gemm_bt<0, 1, 0><<<dim3(8, 8, 16), 256, 0, stream>>>(
            qc, 1024, qstr, qc + 512, 1024, qstr,
            sc, NN, sstr, 512, 0.044194173824159216f, sizes + b0, nullptr);

        // masked softmax in place (wave per row), zero-fill to round64(sz)
        softmax_wave<<<dim3(NN / 4, 16), 256, 0, stream>>>(sc, sizes + b0);

        // y = attn @ v; K bounded at round64(size)
        gemm_bt<0, 0, 1><<<dim3(4, 8, 16), 256, 0, stream>>>(
            sc, NN, sstr, vT + (long long)b0 * vstr, NN, vstr,
            y + (long long)b0 * ystr, ND, ystr, NN, 1.0f, sizes + b0, nullptr);
    }

    // LN2: y -> ln2o (qk hi region, dead)
    ln_kernel<f16><<<NB * NN, 256, 0, stream>>>(y, g2, ln2o);

    // FC + exact GELU: ln2o -> gelub (scoresB region, dead)
    gemm_bt<2, 0, 0><<<dim3(4, 256, 1), 256, 0, stream>>>(
        ln2o, 512, 0, wfcT, 512, 0, gelub, 512, 0, 512, 1.0f, nullptr, nullptr);

    // proj -> out (fp32, overwrites all of d_out; scoresA/y dead)
    gemm_bt<1, 0, 0><<<dim3(4, 256, 1), 256, 0, stream>>>(
        gelub, 512, 0, wprojT, 512, 0, out, 512, 0, 512, 1.0f, nullptr, nullptr);
}